// Round 2
// baseline (167142.065 us; speedup 1.0000x reference)
//
#include <hip/hip_runtime.h>

static constexpr int kH   = 2048;
static constexpr int kS   = 8192;
static constexpr int kNWG = 256;
static constexpr int kTHR = 256;

__device__ __forceinline__ float bflo(unsigned int u) {
    union { unsigned int i; float f; } v; v.i = u << 16; return v.f;
}
__device__ __forceinline__ float bfhi(unsigned int u) {
    union { unsigned int i; float f; } v; v.i = u & 0xffff0000u; return v.f;
}
// round-to-nearest-even f32 pair -> packed bf16x2 (lo in low half)
__device__ __forceinline__ unsigned int pkbf(float lo, float hi) {
    union { float f; unsigned int u; } a, b; a.f = lo; b.f = hi;
    unsigned int ar = a.u + 0x7fffu + ((a.u >> 16) & 1u);
    unsigned int br = b.u + 0x7fffu + ((b.u >> 16) & 1u);
    return (ar >> 16) | (br & 0xffff0000u);
}

// Persistent GRU. Grid = 256 WGs x 256 threads, one WG per CU.
// WG `wg` owns hidden elements e = wg*8..wg*8+7 and all three gate rows for
// them, so the gate combine is WG-local -> ONE grid barrier per step.
// Thread (g,l): element e = wg*8+g, columns c = 8*l + 256*jj + k.
__global__ __launch_bounds__(kTHR, 1)
void gru_persistent(const float* __restrict__ x,    // [S,H] f32
                    const float* __restrict__ Wih,  // [3H,H] f32
                    const float* __restrict__ Whh,  // [3H,H] f32
                    const float* __restrict__ bih,  // [3H] f32
                    const float* __restrict__ bhh,  // [3H] f32
                    float* __restrict__ out,        // [H] f32
                    float* __restrict__ hbuf,       // [2][H] f32 (zeroed)
                    unsigned int* __restrict__ cnt) // zeroed
{
    const int wg  = blockIdx.x;
    const int tid = threadIdx.x;
    const int g   = tid >> 5;
    const int l   = tid & 31;
    const int e   = wg * 8 + g;
    const int cb  = 8 * l;

    // W_hh slice -> fp32 registers (192).  W_ih slice -> packed bf16 (96).
    float whh[3][8][8];
    uint4 wihp[3][8];
#pragma unroll
    for (int G = 0; G < 3; ++G) {
        const size_t row = (size_t)(G * kH + e) * kH;
#pragma unroll
        for (int jj = 0; jj < 8; ++jj) {
            const size_t off = row + cb + 256 * jj;
            const float4 wa = *(const float4*)(Whh + off);
            const float4 wb = *(const float4*)(Whh + off + 4);
            whh[G][jj][0] = wa.x; whh[G][jj][1] = wa.y;
            whh[G][jj][2] = wa.z; whh[G][jj][3] = wa.w;
            whh[G][jj][4] = wb.x; whh[G][jj][5] = wb.y;
            whh[G][jj][6] = wb.z; whh[G][jj][7] = wb.w;
            const float4 ia = *(const float4*)(Wih + off);
            const float4 ib = *(const float4*)(Wih + off + 4);
            wihp[G][jj].x = pkbf(ia.x, ia.y);
            wihp[G][jj].y = pkbf(ia.z, ia.w);
            wihp[G][jj].z = pkbf(ib.x, ib.y);
            wihp[G][jj].w = pkbf(ib.z, ib.w);
        }
    }
    const float bir  = bih[e];
    const float biz  = bih[kH + e];
    const float bin_ = bih[2 * kH + e];
    const float bhr  = bhh[e];
    const float bhz  = bhh[kH + e];
    const float bhn  = bhh[2 * kH + e];

    float hold = 0.0f;  // h for element e (valid on l==0)

#pragma unroll 1
    for (int t = 0; t < kS; ++t) {
        // ---- x projection: independent of h, overlaps the barrier wait ----
        const float* xrow = x + (size_t)t * kH;
        float ar = 0.f, az = 0.f, an = 0.f;
#pragma unroll
        for (int jj = 0; jj < 8; ++jj) {
            const float4 xa = *(const float4*)(xrow + cb + 256 * jj);
            const float4 xb = *(const float4*)(xrow + cb + 256 * jj + 4);
            const float xv[8] = { xa.x, xa.y, xa.z, xa.w, xb.x, xb.y, xb.z, xb.w };
            {
                const uint4 w = wihp[0][jj];
                ar += bflo(w.x)*xv[0] + bfhi(w.x)*xv[1] + bflo(w.y)*xv[2] + bfhi(w.y)*xv[3]
                    + bflo(w.z)*xv[4] + bfhi(w.z)*xv[5] + bflo(w.w)*xv[6] + bfhi(w.w)*xv[7];
            }
            {
                const uint4 w = wihp[1][jj];
                az += bflo(w.x)*xv[0] + bfhi(w.x)*xv[1] + bflo(w.y)*xv[2] + bfhi(w.y)*xv[3]
                    + bflo(w.z)*xv[4] + bfhi(w.z)*xv[5] + bflo(w.w)*xv[6] + bfhi(w.w)*xv[7];
            }
            {
                const uint4 w = wihp[2][jj];
                an += bflo(w.x)*xv[0] + bfhi(w.x)*xv[1] + bflo(w.y)*xv[2] + bfhi(w.y)*xv[3]
                    + bflo(w.z)*xv[4] + bfhi(w.z)*xv[5] + bflo(w.w)*xv[6] + bfhi(w.w)*xv[7];
            }
        }

        // ---- wait until h_t is published by all WGs ----
        if (tid == 0 && t > 0) {
            const unsigned int target = (unsigned int)t * kNWG;
            while (__hip_atomic_load(cnt, __ATOMIC_ACQUIRE, __HIP_MEMORY_SCOPE_AGENT) < target)
                __builtin_amdgcn_s_sleep(2);
        }
        __syncthreads();

        // ---- h projection (critical path) ----
        const float* hcur = hbuf + (size_t)(t & 1) * kH;
        float4 hv[16];
#pragma unroll
        for (int jj = 0; jj < 8; ++jj) {
            hv[2*jj]   = *(const float4*)(hcur + cb + 256 * jj);
            hv[2*jj+1] = *(const float4*)(hcur + cb + 256 * jj + 4);
        }
        float hr = 0.f, hz = 0.f, hn = 0.f;
#pragma unroll
        for (int jj = 0; jj < 8; ++jj) {
            const float hf[8] = { hv[2*jj].x,   hv[2*jj].y,   hv[2*jj].z,   hv[2*jj].w,
                                  hv[2*jj+1].x, hv[2*jj+1].y, hv[2*jj+1].z, hv[2*jj+1].w };
#pragma unroll
            for (int k = 0; k < 8; ++k) {
                hr += whh[0][jj][k] * hf[k];
                hz += whh[1][jj][k] * hf[k];
                hn += whh[2][jj][k] * hf[k];
            }
        }

        // ---- reduce across the 32 lanes owning this element ----
        float pr = ar + hr, pz = az + hz, pxn = an, phn = hn;
#pragma unroll
        for (int m = 16; m >= 1; m >>= 1) {
            pr  += __shfl_xor(pr,  m, 64);
            pz  += __shfl_xor(pz,  m, 64);
            pxn += __shfl_xor(pxn, m, 64);
            phn += __shfl_xor(phn, m, 64);
        }

        if (l == 0) {
            const float r = 1.f / (1.f + __expf(-(pr + bir + bhr)));
            const float z = 1.f / (1.f + __expf(-(pz + biz + bhz)));
            const float a = (pxn + bin_) + r * (phn + bhn);
            // fast-math-robust tanh: denom in [1,2], never inf/inf
            const float ee = __expf(-2.f * fabsf(a));
            float th = (1.f - ee) / (1.f + ee);
            th = (a < 0.f) ? -th : th;
            hold = (1.f - z) * th + z * hold;
            __hip_atomic_store(hbuf + (size_t)((t + 1) & 1) * kH + e, hold,
                               __ATOMIC_RELEASE, __HIP_MEMORY_SCOPE_AGENT);
        }
        __syncthreads();  // each wave drains vmcnt before barrier -> stores acked
        if (tid == 0)
            __hip_atomic_fetch_add(cnt, 1u, __ATOMIC_RELEASE, __HIP_MEMORY_SCOPE_AGENT);
    }

    if (l == 0)
        out[e] = hold;
}

extern "C" void kernel_launch(void* const* d_in, const int* in_sizes, int n_in,
                              void* d_out, int out_size, void* d_ws, size_t ws_size,
                              hipStream_t stream) {
    (void)in_sizes; (void)n_in; (void)out_size; (void)ws_size;
    const float* x   = (const float*)d_in[0];
    const float* Wih = (const float*)d_in[1];
    const float* Whh = (const float*)d_in[2];
    const float* bih = (const float*)d_in[3];
    const float* bhh = (const float*)d_in[4];

    unsigned int* cnt = (unsigned int*)d_ws;            // 4 B (zeroed)
    float* hbuf = (float*)((char*)d_ws + 256);          // 2*H f32 (zeroed)

    hipMemsetAsync(d_ws, 0, 256 + 2 * kH * sizeof(float), stream);
    gru_persistent<<<dim3(kNWG), dim3(kTHR), 0, stream>>>(
        x, Wih, Whh, bih, bhh, (float*)d_out, hbuf, cnt);
}

// Round 3
// 149116.675 us; speedup vs baseline: 1.1209x; 1.1209x over previous
//
#include <hip/hip_runtime.h>

static constexpr int kH   = 2048;
static constexpr int kS   = 8192;
static constexpr int kNWG = 256;
static constexpr int kTHR = 256;

__device__ __forceinline__ float bflo(unsigned int u) {
    union { unsigned int i; float f; } v; v.i = u << 16; return v.f;
}
__device__ __forceinline__ float bfhi(unsigned int u) {
    union { unsigned int i; float f; } v; v.i = u & 0xffff0000u; return v.f;
}
// round-to-nearest-even f32 pair -> packed bf16x2 (lo in low half)
__device__ __forceinline__ unsigned int pkbf(float lo, float hi) {
    union { float f; unsigned int u; } a, b; a.f = lo; b.f = hi;
    unsigned int ar = a.u + 0x7fffu + ((a.u >> 16) & 1u);
    unsigned int br = b.u + 0x7fffu + ((b.u >> 16) & 1u);
    return (ar >> 16) | (br & 0xffff0000u);
}

// Persistent GRU. Grid = 256 WGs x 256 threads, one WG per CU.
// WG `wg` owns hidden elements e = wg*8..wg*8+7 and all three gate rows for
// them, so the gate combine is WG-local -> ONE grid barrier per step.
// Barrier = per-WG flag array (no same-address RMW): arrival is 256 parallel
// release-stores; wait is 4 coalesced relaxed loads + __all, one acquire
// fence after detection.
__global__ __launch_bounds__(kTHR, 1)
void gru_persistent(const float* __restrict__ x,    // [S,H] f32
                    const float* __restrict__ Wih,  // [3H,H] f32
                    const float* __restrict__ Whh,  // [3H,H] f32
                    const float* __restrict__ bih,  // [3H] f32
                    const float* __restrict__ bhh,  // [3H] f32
                    float* __restrict__ out,        // [H] f32
                    float* __restrict__ hbuf,       // [2][H] f32 (zeroed)
                    unsigned int* __restrict__ flags) // [256] (zeroed)
{
    const int wg  = blockIdx.x;
    const int tid = threadIdx.x;
    const int g   = tid >> 5;
    const int l   = tid & 31;
    const int e   = wg * 8 + g;
    const int cb  = 8 * l;

    // W_hh slice -> fp32 registers (192).  W_ih slice -> packed bf16 (96).
    float whh[3][8][8];
    uint4 wihp[3][8];
#pragma unroll
    for (int G = 0; G < 3; ++G) {
        const size_t row = (size_t)(G * kH + e) * kH;
#pragma unroll
        for (int jj = 0; jj < 8; ++jj) {
            const size_t off = row + cb + 256 * jj;
            const float4 wa = *(const float4*)(Whh + off);
            const float4 wb = *(const float4*)(Whh + off + 4);
            whh[G][jj][0] = wa.x; whh[G][jj][1] = wa.y;
            whh[G][jj][2] = wa.z; whh[G][jj][3] = wa.w;
            whh[G][jj][4] = wb.x; whh[G][jj][5] = wb.y;
            whh[G][jj][6] = wb.z; whh[G][jj][7] = wb.w;
            const float4 ia = *(const float4*)(Wih + off);
            const float4 ib = *(const float4*)(Wih + off + 4);
            wihp[G][jj].x = pkbf(ia.x, ia.y);
            wihp[G][jj].y = pkbf(ia.z, ia.w);
            wihp[G][jj].z = pkbf(ib.x, ib.y);
            wihp[G][jj].w = pkbf(ib.z, ib.w);
        }
    }
    const float bir  = bih[e];
    const float biz  = bih[kH + e];
    const float bin_ = bih[2 * kH + e];
    const float bhr  = bhh[e];
    const float bhz  = bhh[kH + e];
    const float bhn  = bhh[2 * kH + e];

    float hold = 0.0f;  // h for element e (valid on l==0)

#pragma unroll 1
    for (int t = 0; t < kS; ++t) {
        // ---- x projection: independent of h, overlaps the barrier wait ----
        const float* xrow = x + (size_t)t * kH;
        float ar = 0.f, az = 0.f, an = 0.f;
#pragma unroll
        for (int jj = 0; jj < 8; ++jj) {
            const float4 xa = *(const float4*)(xrow + cb + 256 * jj);
            const float4 xb = *(const float4*)(xrow + cb + 256 * jj + 4);
            const float xv[8] = { xa.x, xa.y, xa.z, xa.w, xb.x, xb.y, xb.z, xb.w };
            {
                const uint4 w = wihp[0][jj];
                ar += bflo(w.x)*xv[0] + bfhi(w.x)*xv[1] + bflo(w.y)*xv[2] + bfhi(w.y)*xv[3]
                    + bflo(w.z)*xv[4] + bfhi(w.z)*xv[5] + bflo(w.w)*xv[6] + bfhi(w.w)*xv[7];
            }
            {
                const uint4 w = wihp[1][jj];
                az += bflo(w.x)*xv[0] + bfhi(w.x)*xv[1] + bflo(w.y)*xv[2] + bfhi(w.y)*xv[3]
                    + bflo(w.z)*xv[4] + bfhi(w.z)*xv[5] + bflo(w.w)*xv[6] + bfhi(w.w)*xv[7];
            }
            {
                const uint4 w = wihp[2][jj];
                an += bflo(w.x)*xv[0] + bfhi(w.x)*xv[1] + bflo(w.y)*xv[2] + bfhi(w.y)*xv[3]
                    + bflo(w.z)*xv[4] + bfhi(w.z)*xv[5] + bflo(w.w)*xv[6] + bfhi(w.w)*xv[7];
            }
        }

        // ---- wait until h_t is published by all 256 WGs ----
        if (tid < 64 && t > 0) {
            const unsigned int target = (unsigned int)t;
            const unsigned int* f = flags + tid;
            for (;;) {
                const unsigned int f0 = __hip_atomic_load(f,       __ATOMIC_RELAXED, __HIP_MEMORY_SCOPE_AGENT);
                const unsigned int f1 = __hip_atomic_load(f + 64,  __ATOMIC_RELAXED, __HIP_MEMORY_SCOPE_AGENT);
                const unsigned int f2 = __hip_atomic_load(f + 128, __ATOMIC_RELAXED, __HIP_MEMORY_SCOPE_AGENT);
                const unsigned int f3 = __hip_atomic_load(f + 192, __ATOMIC_RELAXED, __HIP_MEMORY_SCOPE_AGENT);
                const int ok = (f0 >= target) & (f1 >= target) &
                               (f2 >= target) & (f3 >= target);
                if (__all(ok)) break;
                __builtin_amdgcn_s_sleep(1);
            }
            // one acquire fence per step (waitcnt + cache invalidate)
            __builtin_amdgcn_fence(__ATOMIC_ACQUIRE, "agent");
        }
        __syncthreads();

        // ---- h projection (critical path) ----
        const float* hcur = hbuf + (size_t)(t & 1) * kH;
        float4 hv[16];
#pragma unroll
        for (int jj = 0; jj < 8; ++jj) {
            hv[2*jj]   = *(const float4*)(hcur + cb + 256 * jj);
            hv[2*jj+1] = *(const float4*)(hcur + cb + 256 * jj + 4);
        }
        float hr = 0.f, hz = 0.f, hn = 0.f;
#pragma unroll
        for (int jj = 0; jj < 8; ++jj) {
            const float hf[8] = { hv[2*jj].x,   hv[2*jj].y,   hv[2*jj].z,   hv[2*jj].w,
                                  hv[2*jj+1].x, hv[2*jj+1].y, hv[2*jj+1].z, hv[2*jj+1].w };
#pragma unroll
            for (int k = 0; k < 8; ++k) {
                hr += whh[0][jj][k] * hf[k];
                hz += whh[1][jj][k] * hf[k];
                hn += whh[2][jj][k] * hf[k];
            }
        }

        // ---- reduce across the 32 lanes owning this element ----
        float pr = ar + hr, pz = az + hz, pxn = an, phn = hn;
#pragma unroll
        for (int m = 16; m >= 1; m >>= 1) {
            pr  += __shfl_xor(pr,  m, 64);
            pz  += __shfl_xor(pz,  m, 64);
            pxn += __shfl_xor(pxn, m, 64);
            phn += __shfl_xor(phn, m, 64);
        }

        if (l == 0) {
            const float r = 1.f / (1.f + __expf(-(pr + bir + bhr)));
            const float z = 1.f / (1.f + __expf(-(pz + biz + bhz)));
            const float a = (pxn + bin_) + r * (phn + bhn);
            // fast-math-robust tanh: denom in [1,2], never inf/inf
            const float ee = __expf(-2.f * fabsf(a));
            float th = (1.f - ee) / (1.f + ee);
            th = (a < 0.f) ? -th : th;
            hold = (1.f - z) * th + z * hold;
            __hip_atomic_store(hbuf + (size_t)((t + 1) & 1) * kH + e, hold,
                               __ATOMIC_RELEASE, __HIP_MEMORY_SCOPE_AGENT);
        }
        __syncthreads();  // compiler drains vmcnt before s_barrier -> h stores acked
        if (tid == 0)
            __hip_atomic_store(flags + wg, (unsigned int)(t + 1),
                               __ATOMIC_RELEASE, __HIP_MEMORY_SCOPE_AGENT);
    }

    if (l == 0)
        out[e] = hold;
}

extern "C" void kernel_launch(void* const* d_in, const int* in_sizes, int n_in,
                              void* d_out, int out_size, void* d_ws, size_t ws_size,
                              hipStream_t stream) {
    (void)in_sizes; (void)n_in; (void)out_size; (void)ws_size;
    const float* x   = (const float*)d_in[0];
    const float* Wih = (const float*)d_in[1];
    const float* Whh = (const float*)d_in[2];
    const float* bih = (const float*)d_in[3];
    const float* bhh = (const float*)d_in[4];

    unsigned int* flags = (unsigned int*)d_ws;              // 256 u32 (zeroed)
    float* hbuf = (float*)((char*)d_ws + 4096);             // 2*H f32 (zeroed)

    hipMemsetAsync(d_ws, 0, 4096 + 2 * kH * sizeof(float), stream);
    gru_persistent<<<dim3(kNWG), dim3(kTHR), 0, stream>>>(
        x, Wih, Whh, bih, bhh, (float*)d_out, hbuf, flags);
}

// Round 4
// 33960.828 us; speedup vs baseline: 4.9216x; 4.3908x over previous
//
#include <hip/hip_runtime.h>

static constexpr int kH   = 2048;
static constexpr int kS   = 8192;
static constexpr int kNWG = 256;
static constexpr int kTHR = 256;

typedef float v4f __attribute__((ext_vector_type(4)));

__device__ __forceinline__ float bflo(unsigned int u) {
    union { unsigned int i; float f; } v; v.i = u << 16; return v.f;
}
__device__ __forceinline__ float bfhi(unsigned int u) {
    union { unsigned int i; float f; } v; v.i = u & 0xffff0000u; return v.f;
}
__device__ __forceinline__ unsigned int pkbf(float lo, float hi) {
    union { float f; unsigned int u; } a, b; a.f = lo; b.f = hi;
    unsigned int ar = a.u + 0x7fffu + ((a.u >> 16) & 1u);
    unsigned int br = b.u + 0x7fffu + ((b.u >> 16) & 1u);
    return (ar >> 16) | (br & 0xffff0000u);
}

// ---- cache-bypassing (MALL-coherent) point accesses: sc0 sc1, no buffer_inv ----
__device__ __forceinline__ void load_f4x2_coh(const float* p, v4f& a, v4f& b) {
    asm volatile("global_load_dwordx4 %0, %2, off sc0 sc1\n\t"
                 "global_load_dwordx4 %1, %2, off offset:16 sc0 sc1\n\t"
                 "s_waitcnt vmcnt(0)"
                 : "=&v"(a), "=&v"(b) : "v"(p) : "memory");
}
__device__ __forceinline__ void load_flags4_coh(const unsigned int* p,
                                                unsigned int& f0, unsigned int& f1,
                                                unsigned int& f2, unsigned int& f3) {
    asm volatile("global_load_dword %0, %4, off sc0 sc1\n\t"
                 "global_load_dword %1, %4, off offset:256 sc0 sc1\n\t"
                 "global_load_dword %2, %4, off offset:512 sc0 sc1\n\t"
                 "global_load_dword %3, %4, off offset:768 sc0 sc1\n\t"
                 "s_waitcnt vmcnt(0)"
                 : "=&v"(f0), "=&v"(f1), "=&v"(f2), "=&v"(f3) : "v"(p) : "memory");
}
__device__ __forceinline__ void store_f_coh_drain(float* p, float v) {
    asm volatile("global_store_dword %0, %1, off sc0 sc1\n\t"
                 "s_waitcnt vmcnt(0)"
                 :: "v"(p), "v"(v) : "memory");
}
__device__ __forceinline__ void store_u_coh(unsigned int* p, unsigned int v) {
    asm volatile("global_store_dword %0, %1, off sc0 sc1"
                 :: "v"(p), "v"(v) : "memory");
}

// Persistent GRU. 256 WGs x 256 threads, one WG per CU. WG owns elements
// e = wg*8..wg*8+7 and all three gate rows -> one grid barrier per step.
// NO agent fences / buffer_inv anywhere in the loop: shared state (h, flags)
// uses explicit sc0 sc1 point accesses; x & weights stay cached.
__global__ __launch_bounds__(kTHR, 1)
void gru_persistent(const float* __restrict__ x,    // [S,H] f32
                    const float* __restrict__ Wih,  // [3H,H] f32
                    const float* __restrict__ Whh,  // [3H,H] f32
                    const float* __restrict__ bih,  // [3H] f32
                    const float* __restrict__ bhh,  // [3H] f32
                    float* __restrict__ out,        // [H] f32
                    float* __restrict__ hbuf,       // [2][H] f32 (zeroed)
                    unsigned int* __restrict__ flags) // [256] (zeroed)
{
    __shared__ float hlds[kH];

    const int wg  = blockIdx.x;
    const int tid = threadIdx.x;
    const int g   = tid >> 5;
    const int l   = tid & 31;
    const int e   = wg * 8 + g;
    const int cb  = 8 * l;

    // W_hh slice -> fp32 registers (192).  W_ih slice -> packed bf16 (96).
    float whh[3][8][8];
    uint4 wihp[3][8];
#pragma unroll
    for (int G = 0; G < 3; ++G) {
        const size_t row = (size_t)(G * kH + e) * kH;
#pragma unroll
        for (int jj = 0; jj < 8; ++jj) {
            const size_t off = row + cb + 256 * jj;
            const float4 wa = *(const float4*)(Whh + off);
            const float4 wb = *(const float4*)(Whh + off + 4);
            whh[G][jj][0] = wa.x; whh[G][jj][1] = wa.y;
            whh[G][jj][2] = wa.z; whh[G][jj][3] = wa.w;
            whh[G][jj][4] = wb.x; whh[G][jj][5] = wb.y;
            whh[G][jj][6] = wb.z; whh[G][jj][7] = wb.w;
            const float4 ia = *(const float4*)(Wih + off);
            const float4 ib = *(const float4*)(Wih + off + 4);
            wihp[G][jj].x = pkbf(ia.x, ia.y);
            wihp[G][jj].y = pkbf(ia.z, ia.w);
            wihp[G][jj].z = pkbf(ib.x, ib.y);
            wihp[G][jj].w = pkbf(ib.z, ib.w);
        }
    }
    const float bir  = bih[e];
    const float biz  = bih[kH + e];
    const float bin_ = bih[2 * kH + e];
    const float bhr  = bhh[e];
    const float bhz  = bhh[kH + e];
    const float bhn  = bhh[2 * kH + e];

    float hold = 0.0f;  // h for element e (valid on l==0)

#pragma unroll 1
    for (int t = 0; t < kS; ++t) {
        // ---- x projection: plain cached loads, overlaps inter-WG skew ----
        const float* xrow = x + (size_t)t * kH;
        float ar = 0.f, az = 0.f, an = 0.f;
#pragma unroll
        for (int jj = 0; jj < 8; ++jj) {
            const float4 xa = *(const float4*)(xrow + cb + 256 * jj);
            const float4 xb = *(const float4*)(xrow + cb + 256 * jj + 4);
            const float xv[8] = { xa.x, xa.y, xa.z, xa.w, xb.x, xb.y, xb.z, xb.w };
            {
                const uint4 w = wihp[0][jj];
                ar += bflo(w.x)*xv[0] + bfhi(w.x)*xv[1] + bflo(w.y)*xv[2] + bfhi(w.y)*xv[3]
                    + bflo(w.z)*xv[4] + bfhi(w.z)*xv[5] + bflo(w.w)*xv[6] + bfhi(w.w)*xv[7];
            }
            {
                const uint4 w = wihp[1][jj];
                az += bflo(w.x)*xv[0] + bfhi(w.x)*xv[1] + bflo(w.y)*xv[2] + bfhi(w.y)*xv[3]
                    + bflo(w.z)*xv[4] + bfhi(w.z)*xv[5] + bflo(w.w)*xv[6] + bfhi(w.w)*xv[7];
            }
            {
                const uint4 w = wihp[2][jj];
                an += bflo(w.x)*xv[0] + bfhi(w.x)*xv[1] + bflo(w.y)*xv[2] + bfhi(w.y)*xv[3]
                    + bflo(w.z)*xv[4] + bfhi(w.z)*xv[5] + bflo(w.w)*xv[6] + bfhi(w.w)*xv[7];
            }
        }

        // ---- wait until h_t is published by all 256 WGs (wave 0 polls) ----
        if (tid < 64 && t > 0) {
            const unsigned int target = (unsigned int)t;
            const unsigned int* f = flags + tid;
            for (;;) {
                unsigned int f0, f1, f2, f3;
                load_flags4_coh(f, f0, f1, f2, f3);
                const int ok = (f0 >= target) & (f1 >= target) &
                               (f2 >= target) & (f3 >= target);
                if (__all(ok)) break;
                __builtin_amdgcn_s_sleep(1);
            }
        }
        __syncthreads();

        // ---- cooperative h gather: 8 KB once per WG, MALL-coherent ----
        {
            const float* hsrc = hbuf + (size_t)(t & 1) * kH + tid * 8;
            v4f ha, hb;
            load_f4x2_coh(hsrc, ha, hb);
            *(v4f*)&hlds[tid * 8]     = ha;
            *(v4f*)&hlds[tid * 8 + 4] = hb;
        }
        __syncthreads();

        // ---- h projection from LDS (critical path) ----
        float hr = 0.f, hz = 0.f, hn = 0.f;
#pragma unroll
        for (int jj = 0; jj < 8; ++jj) {
            const v4f a = *(const v4f*)&hlds[cb + 256 * jj];
            const v4f b = *(const v4f*)&hlds[cb + 256 * jj + 4];
            const float hf[8] = { a[0], a[1], a[2], a[3], b[0], b[1], b[2], b[3] };
#pragma unroll
            for (int k = 0; k < 8; ++k) {
                hr += whh[0][jj][k] * hf[k];
                hz += whh[1][jj][k] * hf[k];
                hn += whh[2][jj][k] * hf[k];
            }
        }

        // ---- reduce across the 32 lanes owning this element ----
        float pr = ar + hr, pz = az + hz, pxn = an, phn = hn;
#pragma unroll
        for (int m = 16; m >= 1; m >>= 1) {
            pr  += __shfl_xor(pr,  m, 64);
            pz  += __shfl_xor(pz,  m, 64);
            pxn += __shfl_xor(pxn, m, 64);
            phn += __shfl_xor(phn, m, 64);
        }

        if (l == 0) {
            const float r = 1.f / (1.f + __expf(-(pr + bir + bhr)));
            const float z = 1.f / (1.f + __expf(-(pz + biz + bhz)));
            const float a = (pxn + bin_) + r * (phn + bhn);
            const float ee = __expf(-2.f * fabsf(a));
            float th = (1.f - ee) / (1.f + ee);
            th = (a < 0.f) ? -th : th;
            hold = (1.f - z) * th + z * hold;
            // write-through to MALL + drain (release half of the publish)
            store_f_coh_drain(hbuf + (size_t)((t + 1) & 1) * kH + e, hold);
        }
        __syncthreads();  // all 8 h stores drained (per-lane waitcnt) + waves joined
        if (tid == 0)
            store_u_coh(flags + wg, (unsigned int)(t + 1));
    }

    if (l == 0)
        out[e] = hold;
}

extern "C" void kernel_launch(void* const* d_in, const int* in_sizes, int n_in,
                              void* d_out, int out_size, void* d_ws, size_t ws_size,
                              hipStream_t stream) {
    (void)in_sizes; (void)n_in; (void)out_size; (void)ws_size;
    const float* x   = (const float*)d_in[0];
    const float* Wih = (const float*)d_in[1];
    const float* Whh = (const float*)d_in[2];
    const float* bih = (const float*)d_in[3];
    const float* bhh = (const float*)d_in[4];

    unsigned int* flags = (unsigned int*)d_ws;              // 256 u32 (zeroed)
    float* hbuf = (float*)((char*)d_ws + 4096);             // 2*H f32 (zeroed)

    hipMemsetAsync(d_ws, 0, 4096 + 2 * kH * sizeof(float), stream);
    gru_persistent<<<dim3(kNWG), dim3(kTHR), 0, stream>>>(
        x, Wih, Whh, bih, bhh, (float*)d_out, hbuf, flags);
}

// Round 5
// 21979.718 us; speedup vs baseline: 7.6044x; 1.5451x over previous
//
#include <hip/hip_runtime.h>
#include <hip/hip_fp16.h>

static constexpr int kH   = 2048;
static constexpr int kS   = 8192;
static constexpr int kNWG = 256;
static constexpr int kTHR = 512;

typedef float        v2f __attribute__((ext_vector_type(2)));
typedef unsigned int v4u __attribute__((ext_vector_type(4)));

__device__ __forceinline__ v2f unpk_bf(unsigned int u) {
    union { unsigned int i; float f; } lo, hi;
    lo.i = u << 16; hi.i = u & 0xffff0000u;
    v2f r; r[0] = lo.f; r[1] = hi.f; return r;
}
__device__ __forceinline__ unsigned int pkbf(float lo, float hi) {
    union { float f; unsigned int u; } a, b; a.f = lo; b.f = hi;
    unsigned int ar = a.u + 0x7fffu + ((a.u >> 16) & 1u);
    unsigned int br = b.u + 0x7fffu + ((b.u >> 16) & 1u);
    return (ar >> 16) | (br & 0xffff0000u);
}
__device__ __forceinline__ v2f cvt2h(unsigned int u) {
    __half2 h = *(__half2*)&u;
    float2 f = __half22float2(h);
    v2f r; r[0] = f.x; r[1] = f.y; return r;
}

// MALL-coherent poll: 4 x dwordx4, 1 KB lane-stride apart, single drain.
__device__ __forceinline__ void poll4(const void* p, v4u& a, v4u& b, v4u& c, v4u& d) {
    asm volatile("global_load_dwordx4 %0, %4, off sc0 sc1\n\t"
                 "global_load_dwordx4 %1, %4, off offset:1024 sc0 sc1\n\t"
                 "global_load_dwordx4 %2, %4, off offset:2048 sc0 sc1\n\t"
                 "global_load_dwordx4 %3, %4, off offset:3072 sc0 sc1\n\t"
                 "s_waitcnt vmcnt(0)"
                 : "=&v"(a), "=&v"(b), "=&v"(c), "=&v"(d) : "v"(p) : "memory");
}
// Single 16B coherent store: h[8] as f16 + embedded toggle bit (one packet).
__device__ __forceinline__ void store16_coh(void* p, v4u v) {
    asm volatile("global_store_dwordx4 %0, %1, off sc0 sc1"
                 :: "v"(p), "v"(v) : "memory");
}

// Persistent GRU. 256 WGs x 512 threads (8 waves), one WG per CU.
// Wave wv owns element e = wg*8+wv; lane l covers cols c = 4l + 256m + k.
// Publish protocol: WG's h[8] as f16 = ONE dwordx4 record; toggle bit
// toggle(s) = ((s>>1)^s)&1 embedded in record LSB; 2 slots (s&1) kill ABA.
// Detect loads ARE the data: zero separate gather, zero drain, zero flag.
__global__ __launch_bounds__(kTHR, 2)
void gru_persistent(const float* __restrict__ x,    // [S,H] f32
                    const float* __restrict__ Wih,  // [3H,H] f32
                    const float* __restrict__ Whh,  // [3H,H] f32
                    const float* __restrict__ bih,  // [3H] f32
                    const float* __restrict__ bhh,  // [3H] f32
                    float* __restrict__ out,        // [H] f32
                    unsigned char* __restrict__ rec) // 2 slots * 4096 B (zeroed)
{
    __shared__ __align__(16) unsigned short hlds[kH];  // h_t as f16, col c at [c]
    __shared__ __align__(16) unsigned short hpub[8];

    const int wg  = blockIdx.x;
    const int tid = threadIdx.x;
    const int wv  = tid >> 6;      // 0..7
    const int l   = tid & 63;      // 0..63
    const int e   = wg * 8 + wv;
    const int cb  = 4 * l;         // cols cb + 256m + k, m<8, k<4

    // Weights: W_hh slice as f32 pairs (96 regs), W_ih as packed bf16 (48).
    v2f   whh2[3][8][2];
    uint2 wihp[3][8];
#pragma unroll
    for (int G = 0; G < 3; ++G) {
        const size_t row = (size_t)(G * kH + e) * kH;
#pragma unroll
        for (int m = 0; m < 8; ++m) {
            const size_t off = row + cb + 256 * m;
            const float4 w = *(const float4*)(Whh + off);
            whh2[G][m][0][0] = w.x; whh2[G][m][0][1] = w.y;
            whh2[G][m][1][0] = w.z; whh2[G][m][1][1] = w.w;
            const float4 iw = *(const float4*)(Wih + off);
            wihp[G][m].x = pkbf(iw.x, iw.y);
            wihp[G][m].y = pkbf(iw.z, iw.w);
        }
    }
    const float bir  = bih[e];
    const float biz  = bih[kH + e];
    const float bin_ = bih[2 * kH + e];
    const float bhr  = bhh[e];
    const float bhz  = bhh[kH + e];
    const float bhn  = bhh[2 * kH + e];

    float hold = 0.0f;  // h for element e (valid on l==0)

#pragma unroll 1
    for (int t = 0; t < kS; ++t) {
        // ---- x projection (cached loads; overlaps inter-WG skew) ----
        const float* xrow = x + (size_t)t * kH;
        v2f ar = {0.f, 0.f}, az = {0.f, 0.f}, an = {0.f, 0.f};
#pragma unroll
        for (int m = 0; m < 8; ++m) {
            const float4 xv = *(const float4*)(xrow + cb + 256 * m);
            v2f x0; x0[0] = xv.x; x0[1] = xv.y;
            v2f x1; x1[0] = xv.z; x1[1] = xv.w;
            ar += unpk_bf(wihp[0][m].x) * x0 + unpk_bf(wihp[0][m].y) * x1;
            az += unpk_bf(wihp[1][m].x) * x0 + unpk_bf(wihp[1][m].y) * x1;
            an += unpk_bf(wihp[2][m].x) * x0 + unpk_bf(wihp[2][m].y) * x1;
        }

        // ---- wave 0: poll all 256 records for step-t toggle; data = payload ----
        if (tid < 64) {
            const unsigned int tg = (unsigned int)(((t >> 1) ^ t) & 1);
            const char* base = (const char*)rec + (t & 1) * 4096 + tid * 16;
            v4u r0, r1, r2, r3;
            for (;;) {
                poll4(base, r0, r1, r2, r3);
                const int ok = ((r0.x & 1u) == tg) & ((r1.x & 1u) == tg) &
                               ((r2.x & 1u) == tg) & ((r3.x & 1u) == tg);
                if (__all(ok)) break;
            }
            // broadcast h_t to LDS: lane i writes records i, i+64, i+128, i+192
            *(v4u*)&hlds[tid * 8]         = r0;
            *(v4u*)&hlds[(tid + 64) * 8]  = r1;
            *(v4u*)&hlds[(tid + 128) * 8] = r2;
            *(v4u*)&hlds[(tid + 192) * 8] = r3;
        }
        __syncthreads();

        // ---- h projection from LDS f16 (lane-contiguous b64 reads) ----
        v2f hr = {0.f, 0.f}, hz = {0.f, 0.f}, hn = {0.f, 0.f};
#pragma unroll
        for (int m = 0; m < 8; ++m) {
            const uint2 hu = *(const uint2*)&hlds[cb + 256 * m];
            const v2f h0 = cvt2h(hu.x);
            const v2f h1 = cvt2h(hu.y);
            hr += whh2[0][m][0] * h0 + whh2[0][m][1] * h1;
            hz += whh2[1][m][0] * h0 + whh2[1][m][1] * h1;
            hn += whh2[2][m][0] * h0 + whh2[2][m][1] * h1;
        }

        // ---- full-wave reduce (64 lanes -> lane 0 of each wave) ----
        float pr  = ar[0] + ar[1] + hr[0] + hr[1];
        float pz  = az[0] + az[1] + hz[0] + hz[1];
        float pxn = an[0] + an[1];
        float phn = hn[0] + hn[1];
#pragma unroll
        for (int m = 32; m >= 1; m >>= 1) {
            pr  += __shfl_xor(pr,  m, 64);
            pz  += __shfl_xor(pz,  m, 64);
            pxn += __shfl_xor(pxn, m, 64);
            phn += __shfl_xor(phn, m, 64);
        }

        if (l == 0) {
            const float r = 1.f / (1.f + __expf(-(pr + bir + bhr)));
            const float z = 1.f / (1.f + __expf(-(pz + biz + bhz)));
            const float a = (pxn + bin_) + r * (phn + bhn);
            const float ee = __expf(-2.f * fabsf(a));
            float th = (1.f - ee) / (1.f + ee);
            th = (a < 0.f) ? -th : th;
            hold = (1.f - z) * th + z * hold;
            const __half hh = __float2half(hold);
            hpub[wv] = *(const unsigned short*)&hh;
        }
        __syncthreads();

        // ---- publish: ONE 16B coherent store (data + toggle in one packet) ----
        if (tid == 0) {
            v4u p = *(const v4u*)hpub;
            const unsigned int tgw = (unsigned int)((((t + 1) >> 1) ^ (t + 1)) & 1);
            p.x = (p.x & ~1u) | tgw;
            store16_coh((char*)rec + ((t + 1) & 1) * 4096 + wg * 16, p);
        }
    }

    if (l == 0)
        out[e] = hold;
}

extern "C" void kernel_launch(void* const* d_in, const int* in_sizes, int n_in,
                              void* d_out, int out_size, void* d_ws, size_t ws_size,
                              hipStream_t stream) {
    (void)in_sizes; (void)n_in; (void)out_size; (void)ws_size;
    const float* x   = (const float*)d_in[0];
    const float* Wih = (const float*)d_in[1];
    const float* Whh = (const float*)d_in[2];
    const float* bih = (const float*)d_in[3];
    const float* bhh = (const float*)d_in[4];

    unsigned char* rec = (unsigned char*)d_ws;   // 2 slots * 4096 B
    hipMemsetAsync(rec, 0, 8192, stream);        // h_0 = 0, slot-0 toggle 0; slot-1 waits
    gru_persistent<<<dim3(kNWG), dim3(kTHR), 0, stream>>>(
        x, Wih, Whh, bih, bhh, (float*)d_out, rec);
}